// Round 6
// baseline (289.967 us; speedup 1.0000x reference)
//
#include <hip/hip_runtime.h>
#include <hip/hip_bf16.h>

#define N_Q 50000
#define H_NB 32
#define K_KP 15
#define C_CH 128
#define KP_EXT 1.2f

typedef __attribute__((ext_vector_type(8))) short bf16x8;   // MFMA A/B operand
typedef __attribute__((ext_vector_type(4))) short bf16x4;   // tr_read b64 result
typedef __attribute__((ext_vector_type(4))) float f32x4;    // MFMA C/D

static __device__ __forceinline__ short f2bf(float f) {
    __hip_bfloat16 h = __float2bfloat16(f);   // RNE
    return *reinterpret_cast<short*>(&h);
}

// prepass: x f32 [N,C] -> bf16 in d_ws (halves gather bytes)
__global__ __launch_bounds__(256)
void cvt_bf16_kernel(const float* __restrict__ x, ushort* __restrict__ xb) {
    const int total = N_Q * C_CH / 4;
    const int stride = gridDim.x * blockDim.x;
    for (int i = blockIdx.x * blockDim.x + threadIdx.x; i < total; i += stride) {
        const float4 v = ((const float4*)x)[i];
        ushort4 o;
        o.x = (ushort)f2bf(v.x);
        o.y = (ushort)f2bf(v.y);
        o.z = (ushort)f2bf(v.z);
        o.w = (ushort)f2bf(v.w);
        ((ushort4*)xb)[i] = o;
    }
}

// One wave per point. P[k,c] = sum_h w[h,k] x[idx_h,c] via 8x mfma 16x16x32.
// Staging: per 16-lane group, ONE dwordx4 gathers a whole 256B bf16 row;
// rows land in per-wave LDS subtiled [ctile 8][h 32][c 16] (s21 layout);
// ds_read_b64_tr_b16 delivers the B-fragment (kdim=h along regs) directly.
__global__ __launch_bounds__(256, 4)
void kpconv_mfma2(const float* __restrict__ q_pts,
                  const float* __restrict__ s_pts,
                  const int*   __restrict__ inds,
                  const float* __restrict__ x,
                  const ushort* __restrict__ xb,
                  const int use_bf,
                  const float* __restrict__ kp,
                  const float* __restrict__ dw,
                  const float* __restrict__ bias,
                  float*       __restrict__ out)
{
    __shared__ __align__(16) ushort s_x[4][4096];   // 8KB per wave

    const int wave = threadIdx.x >> 6;
    const int l    = threadIdx.x & 63;
    const int n    = blockIdx.x * 4 + wave;         // 12500*4 = 50000 exact
    const int lg   = l >> 4;                        // h-block 0..3
    const int ln   = l & 15;                        // k (A) / col (B,C)

    // 8 neighbor indices for this group's rows h = lg*8 + j
    const int4* ip = (const int4*)(inds + n * H_NB + lg * 8);
    const int4 i0 = ip[0], i1 = ip[1];
    const int idxv[8] = {i0.x,i0.y,i0.z,i0.w,i1.x,i1.y,i1.z,i1.w};

    ushort* sxw = &s_x[wave][0];
    // lane ln owns channels c = ln*8 .. ln*8+8 of each row:
    //   ctile = ln>>1, within-tile col base = (ln&1)*8
    const unsigned sslot = (unsigned)((ln >> 1) * 512 + (ln & 1) * 8);

    // ---- issue all 8 row-gathers first (T14: issue-early) ----
    uint4 rv[8];
    if (use_bf) {
#pragma unroll
        for (int i = 0; i < 8; ++i)
            rv[i] = *(const uint4*)(xb + (size_t)(unsigned)idxv[i] * C_CH + ln * 8);
    }

    // ---- A fragment (w) computed per-lane while gathers are in flight ----
    const float qx = q_pts[n*3+0], qy = q_pts[n*3+1], qz = q_pts[n*3+2];
    const int kkc = ln < K_KP ? ln : (K_KP - 1);
    const float kpx = kp[kkc*3+0], kpy = kp[kkc*3+1], kpz = kp[kkc*3+2];

    bf16x8 afrag;
#pragma unroll
    for (int j = 0; j < 8; ++j) {
        const int idx = idxv[j];
        const float px = s_pts[idx*3+0] - qx;
        const float py = s_pts[idx*3+1] - qy;
        const float pz = s_pts[idx*3+2] - qz;
        const float dx = px - kpx, dy = py - kpy, dz = pz - kpz;
        const float d  = sqrtf(fmaf(dx, dx, fmaf(dy, dy, dz*dz)));
        float w = fmaxf(1.0f - d * (1.0f/KP_EXT), 0.0f);
        if (ln == 15) w = 0.0f;                     // pad kernel-point row
        afrag[j] = f2bf(w);
    }

    // ---- write rows to LDS (write-late) ----
    if (use_bf) {
#pragma unroll
        for (int i = 0; i < 8; ++i)
            *(uint4*)(sxw + sslot + (unsigned)((lg*8 + i) * 16)) = rv[i];
    } else {
        // fallback when ws too small: gather f32, convert in-register
#pragma unroll
        for (int i = 0; i < 8; ++i) {
            const float4* rp = (const float4*)(x + (size_t)(unsigned)idxv[i] * C_CH + ln * 8);
            const float4 a = rp[0], b = rp[1];
            bf16x8 tpk;
            tpk[0]=f2bf(a.x); tpk[1]=f2bf(a.y); tpk[2]=f2bf(a.z); tpk[3]=f2bf(a.w);
            tpk[4]=f2bf(b.x); tpk[5]=f2bf(b.y); tpk[6]=f2bf(b.z); tpk[7]=f2bf(b.w);
            *(bf16x8*)(sxw + sslot + (unsigned)((lg*8 + i) * 16)) = tpk;
        }
    }

    // tr_read base: tile t window for group lg = t*1024 + lg*256, lane ln at +ln*8
    const unsigned lbase = (unsigned)(uintptr_t)sxw + (unsigned)(lg * 256 + ln * 8);

    // all LDS writes complete before transpose reads (same wave, no barrier)
    asm volatile("s_waitcnt lgkmcnt(0)" ::: "memory");
    __builtin_amdgcn_sched_barrier(0);

    f32x4 acc[8];
#pragma unroll
    for (int t = 0; t < 8; ++t) acc[t] = (f32x4){0.f, 0.f, 0.f, 0.f};

#define DO_TILE(T, O0, O1)                                                    \
    {                                                                         \
        bf16x4 lo, hi;                                                        \
        asm volatile("ds_read_b64_tr_b16 %0, %2 offset:" O0 "\n\t"            \
                     "ds_read_b64_tr_b16 %1, %2 offset:" O1 "\n\t"            \
                     "s_waitcnt lgkmcnt(0)"                                   \
                     : "=&v"(lo), "=&v"(hi) : "v"(lbase) : "memory");         \
        __builtin_amdgcn_sched_barrier(0);                                    \
        const bf16x8 bfrag = __builtin_shufflevector(lo, hi, 0,1,2,3,4,5,6,7);\
        acc[T] = __builtin_amdgcn_mfma_f32_16x16x32_bf16(afrag, bfrag, acc[T], 0, 0, 0); \
    }

    DO_TILE(0, "0",    "128")
    DO_TILE(1, "1024", "1152")
    DO_TILE(2, "2048", "2176")
    DO_TILE(3, "3072", "3200")
    DO_TILE(4, "4096", "4224")
    DO_TILE(5, "5120", "5248")
    DO_TILE(6, "6144", "6272")
    DO_TILE(7, "7168", "7296")
#undef DO_TILE

    // ---- epilogue: out[c] = sum_k dw[k,c]*P[k,c] + bias[c] ----
    const int rowbase = lg * 4;
#pragma unroll
    for (int t = 0; t < 8; ++t) {
        const int c = t*16 + ln;
        float s = 0.f;
#pragma unroll
        for (int r = 0; r < 4; ++r) {
            const int row = rowbase + r;
            const float dwv = (row < K_KP) ? dw[row * C_CH + c] : 0.f;
            s = fmaf(dwv, acc[t][r], s);
        }
        s += __shfl_xor(s, 16);                 // reduce the 4 row-groups
        s += __shfl_xor(s, 32);
        s += bias[c];
        if (l < 16) out[n * C_CH + c] = s;
    }
}

extern "C" void kernel_launch(void* const* d_in, const int* in_sizes, int n_in,
                              void* d_out, int out_size, void* d_ws, size_t ws_size,
                              hipStream_t stream) {
    const float* q_pts = (const float*)d_in[0];
    const float* s_pts = (const float*)d_in[1];
    const int*   inds  = (const int*)  d_in[2];
    const float* x     = (const float*)d_in[3];
    const float* kp    = (const float*)d_in[4];
    const float* dw    = (const float*)d_in[5];
    const float* bias  = (const float*)d_in[6];
    float* out = (float*)d_out;

    ushort* xb = (ushort*)d_ws;
    const int use_bf = (ws_size >= (size_t)N_Q * C_CH * sizeof(ushort)) ? 1 : 0;
    if (use_bf) {
        cvt_bf16_kernel<<<2048, 256, 0, stream>>>(x, xb);
    }
    kpconv_mfma2<<<N_Q / 4, 256, 0, stream>>>(q_pts, s_pts, inds, x, xb, use_bf,
                                              kp, dw, bias, out);
}

// Round 7
// 168.318 us; speedup vs baseline: 1.7227x; 1.7227x over previous
//
#include <hip/hip_runtime.h>
#include <hip/hip_bf16.h>

#define N_Q 50000
#define H_NB 32
#define K_KP 15
#define C_CH 128
#define KP_EXT 1.2f

typedef __attribute__((ext_vector_type(8))) short bf16x8;   // MFMA A/B operand
typedef __attribute__((ext_vector_type(4))) float f32x4;    // MFMA C/D

static __device__ __forceinline__ short f2bf(float f) {
    __hip_bfloat16 h = __float2bfloat16(f);   // RNE
    return *reinterpret_cast<short*>(&h);
}

// prepass: x f32 [N,C] -> bf16 with channel permutation c' = (c&15)*8 + (c>>4).
// Lane ln's 8 needed channels (c = t*16+ln, t=0..7) become contiguous 16B.
__global__ __launch_bounds__(256)
void cvt_perm_kernel(const float* __restrict__ x, ushort* __restrict__ xb) {
    const int t  = threadIdx.x;
    const int m  = blockIdx.x * 16 + (t >> 4);   // 3125*16 = 50000 exact
    const int ln = t & 15;
    const float* xr = x + (size_t)m * C_CH;
    uint v[8];
#pragma unroll
    for (int i = 0; i < 8; ++i)
        v[i] = (uint)(ushort)f2bf(xr[ln + 16 * i]);
    uint4 o;
    o.x = v[0] | (v[1] << 16);
    o.y = v[2] | (v[3] << 16);
    o.z = v[4] | (v[5] << 16);
    o.w = v[6] | (v[7] << 16);
    *(uint4*)(xb + (size_t)m * C_CH + ln * 8) = o;
}

// One wave per point, register-only (no LDS). P[k,c] = sum_h w[h,k]*x[h,c]
// via 8x mfma_f32_16x16x32_bf16. A (w) computed per-lane in the exact
// fragment layout; B gathered as ONE dwordx4 per row from permuted xb and
// redistributed to tile fragments with compile-time v_perm_b32.
__global__ __launch_bounds__(256, 4)
void kpconv_mfma3(const float* __restrict__ q_pts,
                  const float* __restrict__ s_pts,
                  const int*   __restrict__ inds,
                  const ushort* __restrict__ xb,
                  const float* __restrict__ kp,
                  const float* __restrict__ dw,
                  const float* __restrict__ bias,
                  float*       __restrict__ out)
{
    const int wave = threadIdx.x >> 6;
    const int l    = threadIdx.x & 63;
    const int n    = blockIdx.x * 4 + wave;     // 12500*4 = 50000 exact
    const int lg   = l >> 4;                    // h-block 0..3
    const int ln   = l & 15;                    // k (A) / col (B,C)

    const int4* ip = (const int4*)(inds + n * H_NB + lg * 8);
    const int4 i0 = ip[0], i1 = ip[1];
    const int idxv[8] = {i0.x,i0.y,i0.z,i0.w,i1.x,i1.y,i1.z,i1.w};

    // ---- 8 fat gathers: 16B of permuted bf16 row per lane. Every MFMA tile
    // consumes ALL of rv[0..7], so all 8 loads stay in flight together. ----
    uint4 rv[8];
#pragma unroll
    for (int j = 0; j < 8; ++j)
        rv[j] = *(const uint4*)(xb + (size_t)(unsigned)idxv[j] * C_CH + ln * 8);

    // ---- A fragment (w) while gathers are in flight ----
    const float qx = q_pts[n*3+0], qy = q_pts[n*3+1], qz = q_pts[n*3+2];
    const int kkc = ln < K_KP ? ln : (K_KP - 1);
    const float kpx = kp[kkc*3+0], kpy = kp[kkc*3+1], kpz = kp[kkc*3+2];

    bf16x8 afrag;
#pragma unroll
    for (int j = 0; j < 8; ++j) {
        const int idx = idxv[j];
        const float px = s_pts[idx*3+0] - qx;
        const float py = s_pts[idx*3+1] - qy;
        const float pz = s_pts[idx*3+2] - qz;
        const float dx = px - kpx, dy = py - kpy, dz = pz - kpz;
        const float d  = sqrtf(fmaf(dx, dx, fmaf(dy, dy, dz*dz)));
        float w = fmaxf(1.0f - d * (1.0f/KP_EXT), 0.0f);
        if (ln == 15) w = 0.0f;                 // pad kernel-point row
        afrag[j] = f2bf(w);
    }

    f32x4 acc[8];
#pragma unroll
    for (int t = 0; t < 8; ++t) acc[t] = (f32x4){0.f, 0.f, 0.f, 0.f};

    const uint* rw = (const uint*)&rv[0];       // rv as uint[32]; all indices
                                                // below are compile-time
#pragma unroll
    for (int t = 0; t < 8; ++t) {
        const uint sel = (t & 1) ? 0x07060302u : 0x05040100u;  // pick halfword t&1
        const int  w   = t >> 1;                               // word within uint4
        union { bf16x8 v; uint u[4]; } bf;
#pragma unroll
        for (int r = 0; r < 4; ++r) {
            // dst = [row 2r+1 halfword | row 2r halfword]  (elems 2r, 2r+1)
            bf.u[r] = __builtin_amdgcn_perm(rw[(2*r+1)*4 + w], rw[(2*r)*4 + w], sel);
        }
        acc[t] = __builtin_amdgcn_mfma_f32_16x16x32_bf16(afrag, bf.v, acc[t], 0, 0, 0);
    }

    // ---- epilogue: out[c] = sum_k dw[k,c]*P[k,c] + bias[c] ----
    const int rowbase = lg * 4;
#pragma unroll
    for (int t = 0; t < 8; ++t) {
        const int c = t*16 + ln;
        float s = 0.f;
#pragma unroll
        for (int r = 0; r < 4; ++r) {
            const int row = rowbase + r;
            const float dwv = (row < K_KP) ? dw[row * C_CH + c] : 0.f;
            s = fmaf(dwv, acc[t][r], s);
        }
        s += __shfl_xor(s, 16);                 // reduce the 4 row-groups
        s += __shfl_xor(s, 32);
        s += bias[c];
        if (l < 16) out[n * C_CH + c] = s;
    }
}

// fallback (ws too small): R5's fp32-gather kernel, known-good at 117us
__global__ __launch_bounds__(256, 4)
void kpconv_mfma_fb(const float* __restrict__ q_pts,
                    const float* __restrict__ s_pts,
                    const int*   __restrict__ inds,
                    const float* __restrict__ x,
                    const float* __restrict__ kp,
                    const float* __restrict__ dw,
                    const float* __restrict__ bias,
                    float*       __restrict__ out)
{
    const int wave = threadIdx.x >> 6;
    const int l    = threadIdx.x & 63;
    const int n    = blockIdx.x * 4 + wave;
    const int lg   = l >> 4;
    const int ln   = l & 15;

    const int4* ip = (const int4*)(inds + n * H_NB + lg * 8);
    const int4 i0 = ip[0], i1 = ip[1];
    const int idxv[8] = {i0.x,i0.y,i0.z,i0.w,i1.x,i1.y,i1.z,i1.w};

    const float qx = q_pts[n*3+0], qy = q_pts[n*3+1], qz = q_pts[n*3+2];
    const int kkc = ln < K_KP ? ln : (K_KP - 1);
    const float kpx = kp[kkc*3+0], kpy = kp[kkc*3+1], kpz = kp[kkc*3+2];

    bf16x8 afrag;
#pragma unroll
    for (int j = 0; j < 8; ++j) {
        const int idx = idxv[j];
        const float px = s_pts[idx*3+0] - qx;
        const float py = s_pts[idx*3+1] - qy;
        const float pz = s_pts[idx*3+2] - qz;
        const float dx = px - kpx, dy = py - kpy, dz = pz - kpz;
        const float d  = sqrtf(fmaf(dx, dx, fmaf(dy, dy, dz*dz)));
        float w = fmaxf(1.0f - d * (1.0f/KP_EXT), 0.0f);
        if (ln == 15) w = 0.0f;
        afrag[j] = f2bf(w);
    }

    unsigned boff[8];
#pragma unroll
    for (int j = 0; j < 8; ++j) boff[j] = (unsigned)idxv[j] * C_CH + (unsigned)ln;

    f32x4 acc[8];
#pragma unroll
    for (int t = 0; t < 8; ++t) acc[t] = (f32x4){0.f, 0.f, 0.f, 0.f};
#pragma unroll
    for (int t = 0; t < 8; ++t) {
        bf16x8 bfrag;
#pragma unroll
        for (int j = 0; j < 8; ++j) bfrag[j] = f2bf(x[boff[j] + t*16]);
        acc[t] = __builtin_amdgcn_mfma_f32_16x16x32_bf16(afrag, bfrag, acc[t], 0, 0, 0);
    }

    const int rowbase = lg * 4;
#pragma unroll
    for (int t = 0; t < 8; ++t) {
        const int c = t*16 + ln;
        float s = 0.f;
#pragma unroll
        for (int r = 0; r < 4; ++r) {
            const int row = rowbase + r;
            const float dwv = (row < K_KP) ? dw[row * C_CH + c] : 0.f;
            s = fmaf(dwv, acc[t][r], s);
        }
        s += __shfl_xor(s, 16);
        s += __shfl_xor(s, 32);
        s += bias[c];
        if (l < 16) out[n * C_CH + c] = s;
    }
}

extern "C" void kernel_launch(void* const* d_in, const int* in_sizes, int n_in,
                              void* d_out, int out_size, void* d_ws, size_t ws_size,
                              hipStream_t stream) {
    const float* q_pts = (const float*)d_in[0];
    const float* s_pts = (const float*)d_in[1];
    const int*   inds  = (const int*)  d_in[2];
    const float* x     = (const float*)d_in[3];
    const float* kp    = (const float*)d_in[4];
    const float* dw    = (const float*)d_in[5];
    const float* bias  = (const float*)d_in[6];
    float* out = (float*)d_out;

    if (ws_size >= (size_t)N_Q * C_CH * sizeof(ushort)) {
        ushort* xb = (ushort*)d_ws;
        cvt_perm_kernel<<<N_Q / 16, 256, 0, stream>>>(x, xb);
        kpconv_mfma3<<<N_Q / 4, 256, 0, stream>>>(q_pts, s_pts, inds, xb,
                                                  kp, dw, bias, out);
    } else {
        kpconv_mfma_fb<<<N_Q / 4, 256, 0, stream>>>(q_pts, s_pts, inds, x,
                                                    kp, dw, bias, out);
    }
}